// Round 9
// baseline (614.887 us; speedup 1.0000x reference)
//
#include <hip/hip_runtime.h>
#include <hip/hip_fp16.h>
#include <stdint.h>

#define NN 50000
#define NE 800000
#define SCAN_BLOCKS 196   // 196*256 = 50176 >= NN

typedef _Float16 half8v __attribute__((ext_vector_type(8)));
typedef float f32x4 __attribute__((ext_vector_type(4)));

static __device__ __forceinline__ __half2 u2h2(unsigned int u) {
    union { unsigned int u; __half2 h; } c; c.u = u; return c.h;
}
static __device__ __forceinline__ unsigned int h22u(__half2 h) {
    union { __half2 h; unsigned int u; } c; c.h = h; return c.u;
}

static __device__ __forceinline__ float4 fma4(float4 a, float s, float4 w) {
    a.x = fmaf(s, w.x, a.x); a.y = fmaf(s, w.y, a.y);
    a.z = fmaf(s, w.z, a.z); a.w = fmaf(s, w.w, a.w);
    return a;
}
// acc[8] += relu(h + e); h/e = 16B of packed fp16, math in fp32
static __device__ __forceinline__ void acc8(float* acc, float4 hv, float4 ev) {
    const unsigned int* hu = (const unsigned int*)&hv;
    const unsigned int* eu = (const unsigned int*)&ev;
    #pragma unroll
    for (int q = 0; q < 4; ++q) {
        float2 hf = __half22float2(u2h2(hu[q]));
        float2 ef = __half22float2(u2h2(eu[q]));
        acc[q * 2]     += fmaxf(hf.x + ef.x, 0.f);
        acc[q * 2 + 1] += fmaxf(hf.y + ef.y, 0.f);
    }
}

// ---------- CSR build ----------
__global__ __launch_bounds__(256) void k_deg(const int* __restrict__ ei, int* __restrict__ offcur) {
    int e = blockIdx.x * 256 + threadIdx.x;
    atomicAdd(&offcur[ei[NE + e]], 1);
}

__global__ __launch_bounds__(256) void k_scanA(const int* __restrict__ off, int* __restrict__ part) {
    __shared__ int s[256];
    int t = threadIdx.x;
    int idx = blockIdx.x * 256 + t;
    int d = (idx < NN) ? off[idx] : 0;
    s[t] = d; __syncthreads();
    for (int o = 128; o > 0; o >>= 1) {
        if (t < o) s[t] += s[t + o];
        __syncthreads();
    }
    if (t == 0) part[blockIdx.x] = s[0];
}

__global__ __launch_bounds__(256) void k_scanB(int* __restrict__ part) {
    __shared__ int s[256];
    int t = threadIdx.x;
    int d = (t < SCAN_BLOCKS) ? part[t] : 0;
    s[t] = d; __syncthreads();
    #pragma unroll
    for (int o = 1; o < 256; o <<= 1) {
        int v = (t >= o) ? s[t - o] : 0;
        __syncthreads();
        s[t] += v;
        __syncthreads();
    }
    if (t < SCAN_BLOCKS) part[t] = s[t] - d;   // exclusive
}

__global__ __launch_bounds__(256) void k_scanC(int* __restrict__ off, const int* __restrict__ part) {
    __shared__ int s[256];
    int t = threadIdx.x;
    int idx = blockIdx.x * 256 + t;
    int d = (idx < NN) ? off[idx] : 0;
    s[t] = d; __syncthreads();
    #pragma unroll
    for (int o = 1; o < 256; o <<= 1) {
        int v = (t >= o) ? s[t - o] : 0;
        __syncthreads();
        s[t] += v;
        __syncthreads();
    }
    if (idx < NN) off[idx] = s[t] - d + part[blockIdx.x];
}

// ---------- weight prep: ew2 -> fp16 MFMA B-fragments (once) ----------
__global__ __launch_bounds__(256) void k_prep(const float* __restrict__ ew2, __half* __restrict__ w2f) {
    int tid = threadIdx.x;
    for (int i = tid; i < 4096; i += 256) {
        int k = i >> 6, n = i & 63;
        int kt = k >> 5, kin = k & 31;
        int quad = kin >> 3, j = kin & 7;
        int nt = n >> 4, nin = n & 15;
        w2f[(size_t)((kt * 4 + nt) * 64 + quad * 16 + nin) * 8 + j] = __float2half(ew2[i]);
    }
}

// ---------- h init (fp16 shadow store) ----------
__global__ __launch_bounds__(256) void k_input(const float* __restrict__ x,
        const float* __restrict__ in_w, const float* __restrict__ in_b,
        __half* __restrict__ Ah) {
    int n = blockIdx.x * 4 + (threadIdx.x >> 6);
    int k = threadIdx.x & 63;
    const float* xr = x + (size_t)n * 3;
    float v = in_b[k] + xr[0] * in_w[k] + xr[1] * in_w[64 + k] + xr[2] * in_w[128 + k];
    Ah[(size_t)n * 64 + k] = __float2half(v);
}

// ---------- edge MLP -> ea (fp16) via f16 MFMA, fused CSR scatter ----------
__global__ __launch_bounds__(256) void k_edge(const float* __restrict__ x,
        const int* __restrict__ ei,
        const float* __restrict__ ew1, const float* __restrict__ eb1,
        const float* __restrict__ eb2, const __half* __restrict__ w2f,
        int* __restrict__ offcur, unsigned short* __restrict__ rows,
        __half* __restrict__ ea) {
    __shared__ float s_w1[128], s_b1[64], s_b2[64];
    __shared__ float s_rx[256], s_ry[256];
    __shared__ int s_pos[256];
    __shared__ __half s_d[4][16][80];   // per-wave staging
    int tid = threadIdx.x, lane = tid & 63, w = tid >> 6;

    half8v bf[8];
    {
        const half8v* W2F = (const half8v*)w2f;
        #pragma unroll
        for (int f = 0; f < 8; ++f) bf[f] = W2F[f * 64 + lane];
    }
    if (tid < 128) s_w1[tid] = ew1[tid];
    if (tid < 64) s_b1[tid] = eb1[tid];
    else if (tid < 128) s_b2[tid - 64] = eb2[tid - 64];
    int eb = blockIdx.x * 256;
    int my_r, my_pos;
    {
        int e = eb + tid;
        int r = ei[e], c = ei[NE + e];
        s_rx[tid] = x[(size_t)c * 3]     - x[(size_t)r * 3];
        s_ry[tid] = x[(size_t)c * 3 + 1] - x[(size_t)r * 3 + 1];
        int pos = atomicAdd(&offcur[c], 1);
        my_r = r; my_pos = pos;        // rows[] store deferred to kernel end
        s_pos[tid] = pos;
    }
    __syncthreads();

    int lm = lane & 15, lq = lane >> 4;
    #pragma unroll
    for (int t = 0; t < 4; ++t) {
        int ebase = w * 64 + t * 16;
        float rx = s_rx[ebase + lm], ry = s_ry[ebase + lm];
        half8v a0, a1;
        #pragma unroll
        for (int j = 0; j < 8; ++j) {
            int k0 = lq * 8 + j;
            a0[j] = (_Float16)fmaxf(fmaf(rx, s_w1[k0], fmaf(ry, s_w1[64 + k0], s_b1[k0])), 0.f);
            int k1 = k0 + 32;
            a1[j] = (_Float16)fmaxf(fmaf(rx, s_w1[k1], fmaf(ry, s_w1[64 + k1], s_b1[k1])), 0.f);
        }
        f32x4 acc[4];
        #pragma unroll
        for (int nt = 0; nt < 4; ++nt) {
            float b = s_b2[nt * 16 + lm];
            acc[nt][0] = b; acc[nt][1] = b; acc[nt][2] = b; acc[nt][3] = b;
            acc[nt] = __builtin_amdgcn_mfma_f32_16x16x32_f16(a0, bf[nt],     acc[nt], 0, 0, 0);
            acc[nt] = __builtin_amdgcn_mfma_f32_16x16x32_f16(a1, bf[4 + nt], acc[nt], 0, 0, 0);
        }
        // epilogue: C/D layout col=lane&15, row=(lane>>4)*4+reg -> wave-private LDS
        __builtin_amdgcn_wave_barrier();
        #pragma unroll
        for (int nt = 0; nt < 4; ++nt)
            #pragma unroll
            for (int r = 0; r < 4; ++r)
                s_d[w][lq * 4 + r][nt * 16 + lm] = __float2half(acc[nt][r]);
        __builtin_amdgcn_wave_barrier();
        int row = lane >> 2, seg = lane & 3;
        int pos = s_pos[w * 64 + t * 16 + row];
        uint4 v0 = *(const uint4*)&s_d[w][row][seg * 16];
        uint4 v1 = *(const uint4*)&s_d[w][row][seg * 16 + 8];
        uint4* dst = (uint4*)&ea[(size_t)pos * 64 + seg * 16];
        dst[0] = v0;
        dst[1] = v1;
        __builtin_amdgcn_wave_barrier();
    }
    rows[my_pos] = (unsigned short)my_r;   // deferred scatter, off critical path
}

// ---------- fused per-layer: gather + node MLP + LN + gelu + residual ----------
// block = 64 nodes; phase 1: wave w gathers nodes w*16..w*16+15 into s_m (fp32);
// phase 2: rank-1 MLP on s_m; reads Ain, writes Aout (ping-pong, race-free).
__global__ __launch_bounds__(256) void k_layer(const __half* __restrict__ Ain,
        __half* __restrict__ Aout,
        const __half* __restrict__ ea, const unsigned short* __restrict__ rows,
        const int* __restrict__ off,
        const float* __restrict__ cw1, const float* __restrict__ cb1,
        const float* __restrict__ cw2, const float* __restrict__ cb2,
        const float* __restrict__ lnw, const float* __restrict__ lnb) {
    __shared__ float s_W1[64 * 64];     // [k][c] row-major
    __shared__ float s_W2[64 * 64];
    __shared__ float s_m[64 * 68];      // [node][k], stride 68
    __shared__ float s_b1[64], s_b2[64], s_g[64], s_bt[64];
    int tid = threadIdx.x;
    for (int i = tid; i < 4096; i += 256) { s_W1[i] = cw1[i]; s_W2[i] = cw2[i]; }
    if (tid < 64) { s_b1[tid] = cb1[tid]; s_g[tid] = lnw[tid]; }
    else if (tid < 128) { s_b2[tid - 64] = cb2[tid - 64]; s_bt[tid - 64] = lnb[tid - 64]; }

    int nb = blockIdx.x * 64;
    int lane = tid & 63, w = tid >> 6;

    // ---- phase 1: gather aggregate into s_m ----
    {
        const float4* A4 = (const float4*)Ain;   // 8 fp16 per float4
        const float4* E4 = (const float4*)ea;
        int es = lane >> 3, oc = lane & 7;
        for (int t = 0; t < 16; ++t) {
            int nl = w * 16 + t;
            int n = nb + nl;
            float acc[8] = {0,0,0,0,0,0,0,0};
            float accB[8] = {0,0,0,0,0,0,0,0};
            int p0 = 0, p1 = 0;
            if (n < NN) { p0 = (n == 0) ? 0 : off[n - 1]; p1 = off[n]; }
            for (int base = p0; base < p1; base += 64) {
                int cnt = min(64, p1 - base);
                int rl = (int)rows[base + min(lane, cnt - 1)];
                int j = 0;
                for (; j + 16 <= cnt; j += 16) {
                    int i0 = j + es, i1 = j + 8 + es;
                    int r0 = __shfl(rl, i0, 64);
                    int r1 = __shfl(rl, i1, 64);
                    float4 h0 = A4[(size_t)r0 * 8 + oc];
                    float4 h1 = A4[(size_t)r1 * 8 + oc];
                    float4 e0 = E4[(size_t)(base + i0) * 8 + oc];
                    float4 e1 = E4[(size_t)(base + i1) * 8 + oc];
                    acc8(acc, h0, e0);
                    acc8(accB, h1, e1);
                }
                for (; j < cnt; j += 8) {
                    int i0 = j + es;
                    bool valid = i0 < cnt;
                    int ic = valid ? i0 : (cnt - 1);
                    int r0 = __shfl(rl, ic, 64);
                    float4 h0 = A4[(size_t)r0 * 8 + oc];
                    float4 e0 = E4[(size_t)(base + ic) * 8 + oc];
                    if (valid) acc8(acc, h0, e0);
                }
            }
            #pragma unroll
            for (int q = 0; q < 8; ++q) acc[q] += accB[q];
            #pragma unroll
            for (int m = 8; m < 64; m <<= 1) {
                #pragma unroll
                for (int q = 0; q < 8; ++q) acc[q] += __shfl_xor(acc[q], m, 64);
            }
            if (es == 0) {
                if (n < NN) {
                    float4 sv = A4[(size_t)n * 8 + oc];   // self h
                    const unsigned int* su = (const unsigned int*)&sv;
                    #pragma unroll
                    for (int q = 0; q < 4; ++q) {
                        float2 sf = __half22float2(u2h2(su[q]));
                        acc[q * 2]     += sf.x;
                        acc[q * 2 + 1] += sf.y;
                    }
                }
                float* dst = &s_m[nl * 68 + oc * 8];
                *(float4*)dst       = *(float4*)&acc[0];
                *(float4*)(dst + 4) = *(float4*)&acc[4];
            }
        }
    }
    __syncthreads();

    // ---- phase 2: MLP + LN + gelu + residual ----
    int cq = lane & 15, ng = lane >> 4;
    int rbase = w * 16 + ng * 4;
    int c0 = cq * 4;

    float4 acc[4];
    {
        float4 b1q = *(const float4*)&s_b1[c0];
        acc[0] = b1q; acc[1] = b1q; acc[2] = b1q; acc[3] = b1q;
    }
    #pragma unroll 4
    for (int k4 = 0; k4 < 16; ++k4) {
        float4 m0 = *(const float4*)&s_m[(rbase + 0) * 68 + k4 * 4];
        float4 m1 = *(const float4*)&s_m[(rbase + 1) * 68 + k4 * 4];
        float4 m2 = *(const float4*)&s_m[(rbase + 2) * 68 + k4 * 4];
        float4 m3 = *(const float4*)&s_m[(rbase + 3) * 68 + k4 * 4];
        #pragma unroll
        for (int kk = 0; kk < 4; ++kk) {
            float4 w4 = *(const float4*)&s_W1[(k4 * 4 + kk) * 64 + c0];
            acc[0] = fma4(acc[0], ((const float*)&m0)[kk], w4);
            acc[1] = fma4(acc[1], ((const float*)&m1)[kk], w4);
            acc[2] = fma4(acc[2], ((const float*)&m2)[kk], w4);
            acc[3] = fma4(acc[3], ((const float*)&m3)[kk], w4);
        }
    }
    __builtin_amdgcn_wave_barrier();
    #pragma unroll
    for (int j = 0; j < 4; ++j) {
        float4 u;
        u.x = fmaxf(acc[j].x, 0.f); u.y = fmaxf(acc[j].y, 0.f);
        u.z = fmaxf(acc[j].z, 0.f); u.w = fmaxf(acc[j].w, 0.f);
        *(float4*)&s_m[(rbase + j) * 68 + c0] = u;   // own rows only: wave-local
    }
    __builtin_amdgcn_wave_barrier();

    {
        float4 b2q = *(const float4*)&s_b2[c0];
        acc[0] = b2q; acc[1] = b2q; acc[2] = b2q; acc[3] = b2q;
    }
    #pragma unroll 4
    for (int k4 = 0; k4 < 16; ++k4) {
        float4 m0 = *(const float4*)&s_m[(rbase + 0) * 68 + k4 * 4];
        float4 m1 = *(const float4*)&s_m[(rbase + 1) * 68 + k4 * 4];
        float4 m2 = *(const float4*)&s_m[(rbase + 2) * 68 + k4 * 4];
        float4 m3 = *(const float4*)&s_m[(rbase + 3) * 68 + k4 * 4];
        #pragma unroll
        for (int kk = 0; kk < 4; ++kk) {
            float4 w4 = *(const float4*)&s_W2[(k4 * 4 + kk) * 64 + c0];
            acc[0] = fma4(acc[0], ((const float*)&m0)[kk], w4);
            acc[1] = fma4(acc[1], ((const float*)&m1)[kk], w4);
            acc[2] = fma4(acc[2], ((const float*)&m2)[kk], w4);
            acc[3] = fma4(acc[3], ((const float*)&m3)[kk], w4);
        }
    }

    float4 gq  = *(const float4*)&s_g[c0];
    float4 btq = *(const float4*)&s_bt[c0];
    #pragma unroll
    for (int j = 0; j < 4; ++j) {
        float4 v = acc[j];
        float sum = v.x + v.y + v.z + v.w;
        float sq  = v.x * v.x + v.y * v.y + v.z * v.z + v.w * v.w;
        #pragma unroll
        for (int m = 1; m < 16; m <<= 1) {
            sum += __shfl_xor(sum, m, 64);
            sq  += __shfl_xor(sq, m, 64);
        }
        float mu  = sum * (1.f / 64.f);
        float var = sq * (1.f / 64.f) - mu * mu;
        float rs  = rsqrtf(var + 1e-5f);
        int n = nb + rbase + j;
        if (n < NN) {
            uint2 iu = *(const uint2*)&Ain[(size_t)n * 64 + c0];
            float2 i0 = __half22float2(u2h2(iu.x));
            float2 i1 = __half22float2(u2h2(iu.y));
            float4 o;
            float y;
            y = (v.x - mu) * rs * gq.x + btq.x; o.x = 0.5f * y * (1.f + erff(y * 0.70710678118654752f)) + i0.x;
            y = (v.y - mu) * rs * gq.y + btq.y; o.y = 0.5f * y * (1.f + erff(y * 0.70710678118654752f)) + i0.y;
            y = (v.z - mu) * rs * gq.z + btq.z; o.z = 0.5f * y * (1.f + erff(y * 0.70710678118654752f)) + i1.x;
            y = (v.w - mu) * rs * gq.w + btq.w; o.w = 0.5f * y * (1.f + erff(y * 0.70710678118654752f)) + i1.y;
            uint2 ou;
            ou.x = h22u(__floats2half2_rn(o.x, o.y));
            ou.y = h22u(__floats2half2_rn(o.z, o.w));
            *(uint2*)&Aout[(size_t)n * 64 + c0] = ou;
        }
    }
}

// ---------- final: out = LN(h@(fw+rw) + (fb+rb); ow, ob) ----------
__global__ __launch_bounds__(256) void k_final(const __half* __restrict__ Ah,
        const float* __restrict__ fw, const float* __restrict__ fb,
        const float* __restrict__ rw, const float* __restrict__ rb,
        const float* __restrict__ ow, const float* __restrict__ ob,
        float* __restrict__ out) {
    __shared__ float s_W[64 * 128];     // [k][c] row-major, combined fw+rw
    __shared__ float s_h[32 * 68];
    __shared__ float s_b[128];
    __shared__ float s_red[32][4];
    int tid = threadIdx.x;
    for (int i = tid; i < 8192; i += 256) s_W[i] = fw[i] + rw[i];
    if (tid < 128) s_b[tid] = fb[tid] + rb[tid];
    int nb = blockIdx.x * 32;
    for (int i = tid; i < 2048; i += 256) {
        int nl = i >> 6, k = i & 63;
        int n = nb + nl;
        s_h[nl * 68 + k] = (n < NN) ? __half2float(Ah[(size_t)n * 64 + k]) : 0.f;
    }
    __syncthreads();

    int lane = tid & 63, w = tid >> 6;
    int chh = w & 1, nh = w >> 1;
    int cq = lane & 15, ng = lane >> 4;
    int c0 = chh * 64 + cq * 4;
    int rbase = nh * 16 + ng * 4;

    float4 acc[4];
    {
        float4 bq = *(const float4*)&s_b[c0];
        acc[0] = bq; acc[1] = bq; acc[2] = bq; acc[3] = bq;
    }
    #pragma unroll 4
    for (int k4 = 0; k4 < 16; ++k4) {
        float4 m0 = *(const float4*)&s_h[(rbase + 0) * 68 + k4 * 4];
        float4 m1 = *(const float4*)&s_h[(rbase + 1) * 68 + k4 * 4];
        float4 m2 = *(const float4*)&s_h[(rbase + 2) * 68 + k4 * 4];
        float4 m3 = *(const float4*)&s_h[(rbase + 3) * 68 + k4 * 4];
        #pragma unroll
        for (int kk = 0; kk < 4; ++kk) {
            float4 w4 = *(const float4*)&s_W[(k4 * 4 + kk) * 128 + c0];
            acc[0] = fma4(acc[0], ((const float*)&m0)[kk], w4);
            acc[1] = fma4(acc[1], ((const float*)&m1)[kk], w4);
            acc[2] = fma4(acc[2], ((const float*)&m2)[kk], w4);
            acc[3] = fma4(acc[3], ((const float*)&m3)[kk], w4);
        }
    }
    #pragma unroll
    for (int j = 0; j < 4; ++j) {
        float4 v = acc[j];
        float sum = v.x + v.y + v.z + v.w;
        float sq  = v.x * v.x + v.y * v.y + v.z * v.z + v.w * v.w;
        #pragma unroll
        for (int m = 1; m < 16; m <<= 1) {
            sum += __shfl_xor(sum, m, 64);
            sq  += __shfl_xor(sq, m, 64);
        }
        if (cq == 0) {
            s_red[rbase + j][chh * 2]     = sum;
            s_red[rbase + j][chh * 2 + 1] = sq;
        }
    }
    __syncthreads();
    float4 gq = *(const float4*)&ow[c0];
    float4 bq = *(const float4*)&ob[c0];
    #pragma unroll
    for (int j = 0; j < 4; ++j) {
        int nl = rbase + j;
        int n = nb + nl;
        float tsum = s_red[nl][0] + s_red[nl][2];
        float tsq  = s_red[nl][1] + s_red[nl][3];
        float mu  = tsum * (1.f / 128.f);
        float var = tsq * (1.f / 128.f) - mu * mu;
        float rs  = rsqrtf(var + 1e-5f);
        if (n < NN) {
            float4 v = acc[j];
            float4 o;
            o.x = (v.x - mu) * rs * gq.x + bq.x;
            o.y = (v.y - mu) * rs * gq.y + bq.y;
            o.z = (v.z - mu) * rs * gq.z + bq.z;
            o.w = (v.w - mu) * rs * gq.w + bq.w;
            *(float4*)&out[(size_t)n * 128 + c0] = o;
        }
    }
}

extern "C" void kernel_launch(void* const* d_in, const int* in_sizes, int n_in,
                              void* d_out, int out_size, void* d_ws, size_t ws_size,
                              hipStream_t stream) {
    const float* x    = (const float*)d_in[0];
    const int*   ei   = (const int*)d_in[1];
    const float* in_w = (const float*)d_in[2];
    const float* in_b = (const float*)d_in[3];
    const float* ew1  = (const float*)d_in[4];
    const float* eb1  = (const float*)d_in[5];
    const float* ew2  = (const float*)d_in[6];
    const float* eb2  = (const float*)d_in[7];
    const float* cw1  = (const float*)d_in[8];
    const float* cb1  = (const float*)d_in[9];
    const float* cw2  = (const float*)d_in[10];
    const float* cb2  = (const float*)d_in[11];
    const float* lnw  = (const float*)d_in[12];
    const float* lnb  = (const float*)d_in[13];
    const float* fw   = (const float*)d_in[14];
    const float* fb   = (const float*)d_in[15];
    const float* rw   = (const float*)d_in[16];
    const float* rb   = (const float*)d_in[17];
    const float* ow   = (const float*)d_in[18];
    const float* ob   = (const float*)d_in[19];
    float* out = (float*)d_out;

    // workspace layout (bytes), proven budget 128,000,000:
    //   ea   (fp16): NE*64*2  = 102,400,000  @ 0
    //   Ah0  (fp16): NN*64*2  =   6,400,000  @ 102,400,000
    //   Ah1  (fp16): NN*64*2  =   6,400,000  @ 108,800,000
    //   rows (u16) : NE*2     =   1,600,000  @ 115,200,000
    //   off        : (NN+1)*4 =     200,016  @ 116,800,000
    //   part : SCAN_BLOCKS*4  @ 117,000,016  (dead after prepass)
    //   w2f  : 8 KB           @ 117,100,016  (dead after k_edge)
    char* ws = (char*)d_ws;
    __half*         ea   = (__half*)ws;
    __half*         Ah0  = (__half*)(ws + 102400000);
    __half*         Ah1  = (__half*)(ws + 108800000);
    unsigned short* rows = (unsigned short*)(ws + 115200000);
    int*            off  = (int*)(ws + 116800000);
    int*            part = (int*)(ws + 117000016);
    __half*         w2f  = (__half*)(ws + 117100016);

    (void)hipMemsetAsync(off, 0, (NN + 1) * sizeof(int), stream);
    k_deg<<<NE / 256, 256, 0, stream>>>(ei, off);
    k_scanA<<<SCAN_BLOCKS, 256, 0, stream>>>(off, part);
    k_scanB<<<1, 256, 0, stream>>>(part);
    k_scanC<<<SCAN_BLOCKS, 256, 0, stream>>>(off, part);
    k_prep<<<1, 256, 0, stream>>>(ew2, w2f);
    k_input<<<NN / 4, 256, 0, stream>>>(x, in_w, in_b, Ah0);
    k_edge<<<NE / 256, 256, 0, stream>>>(x, ei, ew1, eb1, eb2, w2f, off, rows, ea);

    const int nodeBlocks = (NN + 63) / 64;     // 782
    __half* Ain = Ah0;
    __half* Aout = Ah1;
    for (int l = 0; l < 4; ++l) {
        k_layer<<<nodeBlocks, 256, 0, stream>>>(Ain, Aout, ea, rows, off,
            cw1 + (size_t)l * 4096, cb1 + (size_t)l * 64,
            cw2 + (size_t)l * 4096, cb2 + (size_t)l * 64,
            lnw + (size_t)l * 64,   lnb + (size_t)l * 64);
        __half* tmp = Ain; Ain = Aout; Aout = tmp;
    }
    // after 4 layers Ain == Ah0
    k_final<<<(NN + 31) / 32, 256, 0, stream>>>(Ain, fw, fb, rw, rb, ow, ob, out);
}

// Round 11
// 509.092 us; speedup vs baseline: 1.2078x; 1.2078x over previous
//
#include <hip/hip_runtime.h>
#include <hip/hip_fp16.h>
#include <stdint.h>

#define NN 50000
#define NE 800000
#define SCAN_BLOCKS 196   // 196*256 = 50176 >= NN

typedef _Float16 half8v __attribute__((ext_vector_type(8)));
typedef float f32x4 __attribute__((ext_vector_type(4)));
typedef unsigned int u32x4 __attribute__((ext_vector_type(4)));

static __device__ __forceinline__ __half2 u2h2(unsigned int u) {
    union { unsigned int u; __half2 h; } c; c.u = u; return c.h;
}
static __device__ __forceinline__ unsigned int h22u(__half2 h) {
    union { __half2 h; unsigned int u; } c; c.h = h; return c.u;
}

static __device__ __forceinline__ float4 fma4(float4 a, float s, float4 w) {
    a.x = fmaf(s, w.x, a.x); a.y = fmaf(s, w.y, a.y);
    a.z = fmaf(s, w.z, a.z); a.w = fmaf(s, w.w, a.w);
    return a;
}
// acc[8] += relu(h + e); h/e = 16B of packed fp16 (as f32x4 bits), math in fp32
static __device__ __forceinline__ void acc8(float* acc, f32x4 hv, f32x4 ev) {
    const unsigned int* hu = (const unsigned int*)&hv;
    const unsigned int* eu = (const unsigned int*)&ev;
    #pragma unroll
    for (int q = 0; q < 4; ++q) {
        float2 hf = __half22float2(u2h2(hu[q]));
        float2 ef = __half22float2(u2h2(eu[q]));
        acc[q * 2]     += fmaxf(hf.x + ef.x, 0.f);
        acc[q * 2 + 1] += fmaxf(hf.y + ef.y, 0.f);
    }
}

// ---------- CSR build ----------
__global__ __launch_bounds__(256) void k_deg(const int* __restrict__ ei, int* __restrict__ offcur) {
    int e = blockIdx.x * 256 + threadIdx.x;
    atomicAdd(&offcur[ei[NE + e]], 1);
}

__global__ __launch_bounds__(256) void k_scanA(const int* __restrict__ off, int* __restrict__ part) {
    __shared__ int s[256];
    int t = threadIdx.x;
    int idx = blockIdx.x * 256 + t;
    int d = (idx < NN) ? off[idx] : 0;
    s[t] = d; __syncthreads();
    for (int o = 128; o > 0; o >>= 1) {
        if (t < o) s[t] += s[t + o];
        __syncthreads();
    }
    if (t == 0) part[blockIdx.x] = s[0];
}

__global__ __launch_bounds__(256) void k_scanB(int* __restrict__ part) {
    __shared__ int s[256];
    int t = threadIdx.x;
    int d = (t < SCAN_BLOCKS) ? part[t] : 0;
    s[t] = d; __syncthreads();
    #pragma unroll
    for (int o = 1; o < 256; o <<= 1) {
        int v = (t >= o) ? s[t - o] : 0;
        __syncthreads();
        s[t] += v;
        __syncthreads();
    }
    if (t < SCAN_BLOCKS) part[t] = s[t] - d;   // exclusive
}

__global__ __launch_bounds__(256) void k_scanC(int* __restrict__ off, const int* __restrict__ part) {
    __shared__ int s[256];
    int t = threadIdx.x;
    int idx = blockIdx.x * 256 + t;
    int d = (idx < NN) ? off[idx] : 0;
    s[t] = d; __syncthreads();
    #pragma unroll
    for (int o = 1; o < 256; o <<= 1) {
        int v = (t >= o) ? s[t - o] : 0;
        __syncthreads();
        s[t] += v;
        __syncthreads();
    }
    if (idx < NN) off[idx] = s[t] - d + part[blockIdx.x];
}

// ---------- weight prep: ew2 -> fp16 MFMA B-fragments (once) ----------
__global__ __launch_bounds__(256) void k_prep(const float* __restrict__ ew2, __half* __restrict__ w2f) {
    int tid = threadIdx.x;
    for (int i = tid; i < 4096; i += 256) {
        int k = i >> 6, n = i & 63;
        int kt = k >> 5, kin = k & 31;
        int quad = kin >> 3, j = kin & 7;
        int nt = n >> 4, nin = n & 15;
        w2f[(size_t)((kt * 4 + nt) * 64 + quad * 16 + nin) * 8 + j] = __float2half(ew2[i]);
    }
}

// ---------- h init (fp16 shadow store) ----------
__global__ __launch_bounds__(256) void k_input(const float* __restrict__ x,
        const float* __restrict__ in_w, const float* __restrict__ in_b,
        __half* __restrict__ Ah) {
    int n = blockIdx.x * 4 + (threadIdx.x >> 6);
    int k = threadIdx.x & 63;
    const float* xr = x + (size_t)n * 3;
    float v = in_b[k] + xr[0] * in_w[k] + xr[1] * in_w[64 + k] + xr[2] * in_w[128 + k];
    Ah[(size_t)n * 64 + k] = __float2half(v);
}

// ---------- edge MLP -> ea (fp16) via f16 MFMA, fused CSR scatter ----------
__global__ __launch_bounds__(256) void k_edge(const float* __restrict__ x,
        const int* __restrict__ ei,
        const float* __restrict__ ew1, const float* __restrict__ eb1,
        const float* __restrict__ eb2, const __half* __restrict__ w2f,
        int* __restrict__ offcur, unsigned short* __restrict__ rows,
        __half* __restrict__ ea) {
    __shared__ float s_w1[128], s_b1[64], s_b2[64];
    __shared__ float s_rx[256], s_ry[256];
    __shared__ int s_pos[256];
    __shared__ __half s_d[4][16][80];   // per-wave staging
    int tid = threadIdx.x, lane = tid & 63, w = tid >> 6;

    half8v bf[8];
    {
        const half8v* W2F = (const half8v*)w2f;
        #pragma unroll
        for (int f = 0; f < 8; ++f) bf[f] = W2F[f * 64 + lane];
    }
    if (tid < 128) s_w1[tid] = ew1[tid];
    if (tid < 64) s_b1[tid] = eb1[tid];
    else if (tid < 128) s_b2[tid - 64] = eb2[tid - 64];
    int eb = blockIdx.x * 256;
    int my_r, my_pos;
    {
        int e = eb + tid;
        int r = ei[e], c = ei[NE + e];
        s_rx[tid] = x[(size_t)c * 3]     - x[(size_t)r * 3];
        s_ry[tid] = x[(size_t)c * 3 + 1] - x[(size_t)r * 3 + 1];
        int pos = atomicAdd(&offcur[c], 1);
        my_r = r; my_pos = pos;        // rows[] store deferred to kernel end
        s_pos[tid] = pos;
    }
    __syncthreads();

    int lm = lane & 15, lq = lane >> 4;
    #pragma unroll
    for (int t = 0; t < 4; ++t) {
        int ebase = w * 64 + t * 16;
        float rx = s_rx[ebase + lm], ry = s_ry[ebase + lm];
        half8v a0, a1;
        #pragma unroll
        for (int j = 0; j < 8; ++j) {
            int k0 = lq * 8 + j;
            a0[j] = (_Float16)fmaxf(fmaf(rx, s_w1[k0], fmaf(ry, s_w1[64 + k0], s_b1[k0])), 0.f);
            int k1 = k0 + 32;
            a1[j] = (_Float16)fmaxf(fmaf(rx, s_w1[k1], fmaf(ry, s_w1[64 + k1], s_b1[k1])), 0.f);
        }
        f32x4 acc[4];
        #pragma unroll
        for (int nt = 0; nt < 4; ++nt) {
            float b = s_b2[nt * 16 + lm];
            acc[nt][0] = b; acc[nt][1] = b; acc[nt][2] = b; acc[nt][3] = b;
            acc[nt] = __builtin_amdgcn_mfma_f32_16x16x32_f16(a0, bf[nt],     acc[nt], 0, 0, 0);
            acc[nt] = __builtin_amdgcn_mfma_f32_16x16x32_f16(a1, bf[4 + nt], acc[nt], 0, 0, 0);
        }
        // epilogue: C/D layout col=lane&15, row=(lane>>4)*4+reg -> wave-private LDS
        __builtin_amdgcn_wave_barrier();
        #pragma unroll
        for (int nt = 0; nt < 4; ++nt)
            #pragma unroll
            for (int r = 0; r < 4; ++r)
                s_d[w][lq * 4 + r][nt * 16 + lm] = __float2half(acc[nt][r]);
        __builtin_amdgcn_wave_barrier();
        int row = lane >> 2, seg = lane & 3;
        int pos = s_pos[w * 64 + t * 16 + row];
        u32x4 v0 = *(const u32x4*)&s_d[w][row][seg * 16];
        u32x4 v1 = *(const u32x4*)&s_d[w][row][seg * 16 + 8];
        u32x4* dst = (u32x4*)&ea[(size_t)pos * 64 + seg * 16];
        __builtin_nontemporal_store(v0, dst);       // ea is stream-out: keep L2 clean
        __builtin_nontemporal_store(v1, dst + 1);
        __builtin_amdgcn_wave_barrier();
    }
    rows[my_pos] = (unsigned short)my_r;   // deferred scatter, off critical path
}

// ---------- per-layer: gather aggregate ----------
// wave per node; lane = es (8 edge sublanes) x oc (8 channel octets of 16B).
// ea read via nontemporal loads (102MB stream must not evict Ah from L2).
__global__ __launch_bounds__(256) void k_agg(const __half* __restrict__ Ah,
        const __half* __restrict__ ea, const unsigned short* __restrict__ rows,
        const int* __restrict__ offcur, __half* __restrict__ M) {
    const f32x4* A4 = (const f32x4*)Ah;   // 8 fp16 per f32x4
    const f32x4* E4 = (const f32x4*)ea;
    int w = threadIdx.x >> 6, lane = threadIdx.x & 63;
    int es = lane >> 3, oc = lane & 7;
    int n = blockIdx.x * 4 + w;
    int p0 = (n == 0) ? 0 : offcur[n - 1];
    int p1 = offcur[n];
    float acc[8] = {0,0,0,0,0,0,0,0};
    float accB[8] = {0,0,0,0,0,0,0,0};
    for (int base = p0; base < p1; base += 64) {
        int cnt = min(64, p1 - base);
        int rl = (int)rows[base + min(lane, cnt - 1)];
        int j = 0;
        for (; j + 16 <= cnt; j += 16) {
            int i0 = j + es, i1 = j + 8 + es;
            int r0 = __shfl(rl, i0, 64);
            int r1 = __shfl(rl, i1, 64);
            f32x4 h0 = A4[(size_t)r0 * 8 + oc];
            f32x4 h1 = A4[(size_t)r1 * 8 + oc];
            f32x4 e0 = __builtin_nontemporal_load(&E4[(size_t)(base + i0) * 8 + oc]);
            f32x4 e1 = __builtin_nontemporal_load(&E4[(size_t)(base + i1) * 8 + oc]);
            acc8(acc, h0, e0);
            acc8(accB, h1, e1);
        }
        for (; j < cnt; j += 8) {
            int i0 = j + es;
            bool valid = i0 < cnt;
            int ic = valid ? i0 : (cnt - 1);
            int r0 = __shfl(rl, ic, 64);
            f32x4 h0 = A4[(size_t)r0 * 8 + oc];
            f32x4 e0 = __builtin_nontemporal_load(&E4[(size_t)(base + ic) * 8 + oc]);
            if (valid) acc8(acc, h0, e0);
        }
    }
    #pragma unroll
    for (int q = 0; q < 8; ++q) acc[q] += accB[q];
    #pragma unroll
    for (int m = 8; m < 64; m <<= 1) {
        #pragma unroll
        for (int q = 0; q < 8; ++q) acc[q] += __shfl_xor(acc[q], m, 64);
    }
    if (es == 0) {
        f32x4 sv = A4[(size_t)n * 8 + oc];
        const unsigned int* su = (const unsigned int*)&sv;
        unsigned int o[4];
        #pragma unroll
        for (int q = 0; q < 4; ++q) {
            float2 sf = __half22float2(u2h2(su[q]));
            o[q] = h22u(__floats2half2_rn(sf.x + acc[q * 2], sf.y + acc[q * 2 + 1]));
        }
        *(uint4*)&M[(size_t)n * 64 + oc * 8] = *(uint4*)&o[0];
    }
}

// ---------- per-layer: node MLP + LN + gelu + residual (fp16 A, fp16 M) ----------
__global__ __launch_bounds__(256) void k_node(__half* __restrict__ Ah, const __half* __restrict__ M,
        const float* __restrict__ cw1, const float* __restrict__ cb1,
        const float* __restrict__ cw2, const float* __restrict__ cb2,
        const float* __restrict__ lnw, const float* __restrict__ lnb) {
    __shared__ float s_W1[64 * 64];     // [k][c] row-major
    __shared__ float s_W2[64 * 64];
    __shared__ float s_m[64 * 68];      // [node][k], stride 68
    __shared__ float s_b1[64], s_b2[64], s_g[64], s_bt[64];
    int tid = threadIdx.x;
    for (int i = tid; i < 4096; i += 256) { s_W1[i] = cw1[i]; s_W2[i] = cw2[i]; }
    if (tid < 64) { s_b1[tid] = cb1[tid]; s_g[tid] = lnw[tid]; }
    else if (tid < 128) { s_b2[tid - 64] = cb2[tid - 64]; s_bt[tid - 64] = lnb[tid - 64]; }
    int nb = blockIdx.x * 64;
    {
        const uint4* M4 = (const uint4*)(M + (size_t)nb * 64);   // 8 fp16 per uint4
        #pragma unroll
        for (int q = 0; q < 2; ++q) {
            int i = q * 256 + tid;          // uint4 index within block tile (512 total)
            int nl = i >> 3;
            int k8 = (i & 7) * 8;
            uint4 v = {0, 0, 0, 0};
            if (nb + nl < NN) v = M4[i];
            float* dst = &s_m[nl * 68 + k8];
            const unsigned int* vu = (const unsigned int*)&v;
            #pragma unroll
            for (int p = 0; p < 4; ++p) {
                float2 f = __half22float2(u2h2(vu[p]));
                dst[p * 2] = f.x; dst[p * 2 + 1] = f.y;
            }
        }
    }
    __syncthreads();

    int lane = tid & 63, w = tid >> 6;
    int cq = lane & 15, ng = lane >> 4;
    int rbase = w * 16 + ng * 4;
    int c0 = cq * 4;

    float4 acc[4];
    {
        float4 b1q = *(const float4*)&s_b1[c0];
        acc[0] = b1q; acc[1] = b1q; acc[2] = b1q; acc[3] = b1q;
    }
    #pragma unroll 4
    for (int k4 = 0; k4 < 16; ++k4) {
        float4 m0 = *(const float4*)&s_m[(rbase + 0) * 68 + k4 * 4];
        float4 m1 = *(const float4*)&s_m[(rbase + 1) * 68 + k4 * 4];
        float4 m2 = *(const float4*)&s_m[(rbase + 2) * 68 + k4 * 4];
        float4 m3 = *(const float4*)&s_m[(rbase + 3) * 68 + k4 * 4];
        #pragma unroll
        for (int kk = 0; kk < 4; ++kk) {
            float4 w4 = *(const float4*)&s_W1[(k4 * 4 + kk) * 64 + c0];
            acc[0] = fma4(acc[0], ((const float*)&m0)[kk], w4);
            acc[1] = fma4(acc[1], ((const float*)&m1)[kk], w4);
            acc[2] = fma4(acc[2], ((const float*)&m2)[kk], w4);
            acc[3] = fma4(acc[3], ((const float*)&m3)[kk], w4);
        }
    }
    __builtin_amdgcn_wave_barrier();
    #pragma unroll
    for (int j = 0; j < 4; ++j) {
        float4 u;
        u.x = fmaxf(acc[j].x, 0.f); u.y = fmaxf(acc[j].y, 0.f);
        u.z = fmaxf(acc[j].z, 0.f); u.w = fmaxf(acc[j].w, 0.f);
        *(float4*)&s_m[(rbase + j) * 68 + c0] = u;   // own rows only: wave-local
    }
    __builtin_amdgcn_wave_barrier();

    {
        float4 b2q = *(const float4*)&s_b2[c0];
        acc[0] = b2q; acc[1] = b2q; acc[2] = b2q; acc[3] = b2q;
    }
    #pragma unroll 4
    for (int k4 = 0; k4 < 16; ++k4) {
        float4 m0 = *(const float4*)&s_m[(rbase + 0) * 68 + k4 * 4];
        float4 m1 = *(const float4*)&s_m[(rbase + 1) * 68 + k4 * 4];
        float4 m2 = *(const float4*)&s_m[(rbase + 2) * 68 + k4 * 4];
        float4 m3 = *(const float4*)&s_m[(rbase + 3) * 68 + k4 * 4];
        #pragma unroll
        for (int kk = 0; kk < 4; ++kk) {
            float4 w4 = *(const float4*)&s_W2[(k4 * 4 + kk) * 64 + c0];
            acc[0] = fma4(acc[0], ((const float*)&m0)[kk], w4);
            acc[1] = fma4(acc[1], ((const float*)&m1)[kk], w4);
            acc[2] = fma4(acc[2], ((const float*)&m2)[kk], w4);
            acc[3] = fma4(acc[3], ((const float*)&m3)[kk], w4);
        }
    }

    float4 gq  = *(const float4*)&s_g[c0];
    float4 btq = *(const float4*)&s_bt[c0];
    #pragma unroll
    for (int j = 0; j < 4; ++j) {
        float4 v = acc[j];
        float sum = v.x + v.y + v.z + v.w;
        float sq  = v.x * v.x + v.y * v.y + v.z * v.z + v.w * v.w;
        #pragma unroll
        for (int m = 1; m < 16; m <<= 1) {
            sum += __shfl_xor(sum, m, 64);
            sq  += __shfl_xor(sq, m, 64);
        }
        float mu  = sum * (1.f / 64.f);
        float var = sq * (1.f / 64.f) - mu * mu;
        float rs  = rsqrtf(var + 1e-5f);
        int n = nb + rbase + j;
        if (n < NN) {
            uint2 iu = *(const uint2*)&Ah[(size_t)n * 64 + c0];
            float2 i0 = __half22float2(u2h2(iu.x));
            float2 i1 = __half22float2(u2h2(iu.y));
            float4 o;
            float y;
            y = (v.x - mu) * rs * gq.x + btq.x; o.x = 0.5f * y * (1.f + erff(y * 0.70710678118654752f)) + i0.x;
            y = (v.y - mu) * rs * gq.y + btq.y; o.y = 0.5f * y * (1.f + erff(y * 0.70710678118654752f)) + i0.y;
            y = (v.z - mu) * rs * gq.z + btq.z; o.z = 0.5f * y * (1.f + erff(y * 0.70710678118654752f)) + i1.x;
            y = (v.w - mu) * rs * gq.w + btq.w; o.w = 0.5f * y * (1.f + erff(y * 0.70710678118654752f)) + i1.y;
            uint2 ou;
            ou.x = h22u(__floats2half2_rn(o.x, o.y));
            ou.y = h22u(__floats2half2_rn(o.z, o.w));
            *(uint2*)&Ah[(size_t)n * 64 + c0] = ou;
        }
    }
}

// ---------- final: out = LN(h@(fw+rw) + (fb+rb); ow, ob) ----------
__global__ __launch_bounds__(256) void k_final(const __half* __restrict__ Ah,
        const float* __restrict__ fw, const float* __restrict__ fb,
        const float* __restrict__ rw, const float* __restrict__ rb,
        const float* __restrict__ ow, const float* __restrict__ ob,
        float* __restrict__ out) {
    __shared__ float s_W[64 * 128];     // [k][c] row-major, combined fw+rw
    __shared__ float s_h[32 * 68];
    __shared__ float s_b[128];
    __shared__ float s_red[32][4];
    int tid = threadIdx.x;
    for (int i = tid; i < 8192; i += 256) s_W[i] = fw[i] + rw[i];
    if (tid < 128) s_b[tid] = fb[tid] + rb[tid];
    int nb = blockIdx.x * 32;
    for (int i = tid; i < 2048; i += 256) {
        int nl = i >> 6, k = i & 63;
        int n = nb + nl;
        s_h[nl * 68 + k] = (n < NN) ? __half2float(Ah[(size_t)n * 64 + k]) : 0.f;
    }
    __syncthreads();

    int lane = tid & 63, w = tid >> 6;
    int chh = w & 1, nh = w >> 1;
    int cq = lane & 15, ng = lane >> 4;
    int c0 = chh * 64 + cq * 4;
    int rbase = nh * 16 + ng * 4;

    float4 acc[4];
    {
        float4 bq = *(const float4*)&s_b[c0];
        acc[0] = bq; acc[1] = bq; acc[2] = bq; acc[3] = bq;
    }
    #pragma unroll 4
    for (int k4 = 0; k4 < 16; ++k4) {
        float4 m0 = *(const float4*)&s_h[(rbase + 0) * 68 + k4 * 4];
        float4 m1 = *(const float4*)&s_h[(rbase + 1) * 68 + k4 * 4];
        float4 m2 = *(const float4*)&s_h[(rbase + 2) * 68 + k4 * 4];
        float4 m3 = *(const float4*)&s_h[(rbase + 3) * 68 + k4 * 4];
        #pragma unroll
        for (int kk = 0; kk < 4; ++kk) {
            float4 w4 = *(const float4*)&s_W[(k4 * 4 + kk) * 128 + c0];
            acc[0] = fma4(acc[0], ((const float*)&m0)[kk], w4);
            acc[1] = fma4(acc[1], ((const float*)&m1)[kk], w4);
            acc[2] = fma4(acc[2], ((const float*)&m2)[kk], w4);
            acc[3] = fma4(acc[3], ((const float*)&m3)[kk], w4);
        }
    }
    #pragma unroll
    for (int j = 0; j < 4; ++j) {
        float4 v = acc[j];
        float sum = v.x + v.y + v.z + v.w;
        float sq  = v.x * v.x + v.y * v.y + v.z * v.z + v.w * v.w;
        #pragma unroll
        for (int m = 1; m < 16; m <<= 1) {
            sum += __shfl_xor(sum, m, 64);
            sq  += __shfl_xor(sq, m, 64);
        }
        if (cq == 0) {
            s_red[rbase + j][chh * 2]     = sum;
            s_red[rbase + j][chh * 2 + 1] = sq;
        }
    }
    __syncthreads();
    float4 gq = *(const float4*)&ow[c0];
    float4 bq = *(const float4*)&ob[c0];
    #pragma unroll
    for (int j = 0; j < 4; ++j) {
        int nl = rbase + j;
        int n = nb + nl;
        float tsum = s_red[nl][0] + s_red[nl][2];
        float tsq  = s_red[nl][1] + s_red[nl][3];
        float mu  = tsum * (1.f / 128.f);
        float var = tsq * (1.f / 128.f) - mu * mu;
        float rs  = rsqrtf(var + 1e-5f);
        if (n < NN) {
            float4 v = acc[j];
            float4 o;
            o.x = (v.x - mu) * rs * gq.x + bq.x;
            o.y = (v.y - mu) * rs * gq.y + bq.y;
            o.z = (v.z - mu) * rs * gq.z + bq.z;
            o.w = (v.w - mu) * rs * gq.w + bq.w;
            *(float4*)&out[(size_t)n * 128 + c0] = o;
        }
    }
}

extern "C" void kernel_launch(void* const* d_in, const int* in_sizes, int n_in,
                              void* d_out, int out_size, void* d_ws, size_t ws_size,
                              hipStream_t stream) {
    const float* x    = (const float*)d_in[0];
    const int*   ei   = (const int*)d_in[1];
    const float* in_w = (const float*)d_in[2];
    const float* in_b = (const float*)d_in[3];
    const float* ew1  = (const float*)d_in[4];
    const float* eb1  = (const float*)d_in[5];
    const float* ew2  = (const float*)d_in[6];
    const float* eb2  = (const float*)d_in[7];
    const float* cw1  = (const float*)d_in[8];
    const float* cb1  = (const float*)d_in[9];
    const float* cw2  = (const float*)d_in[10];
    const float* cb2  = (const float*)d_in[11];
    const float* lnw  = (const float*)d_in[12];
    const float* lnb  = (const float*)d_in[13];
    const float* fw   = (const float*)d_in[14];
    const float* fb   = (const float*)d_in[15];
    const float* rw   = (const float*)d_in[16];
    const float* rb   = (const float*)d_in[17];
    const float* ow   = (const float*)d_in[18];
    const float* ob   = (const float*)d_in[19];
    float* out = (float*)d_out;

    // workspace layout (bytes), proven budget 128,000,000:
    //   ea   (fp16): NE*64*2  = 102,400,000  @ 0
    //   Ah   (fp16): NN*64*2  =   6,400,000  @ 102,400,000
    //   rows (u16) : NE*2     =   1,600,000  @ 108,800,000
    //   off        : (NN+1)*4 =     200,016  @ 110,400,000
    //   M    (fp16): NN*64*2  =   6,400,000  @ 110,600,016  (ends 117,000,016)
    //   part : SCAN_BLOCKS*4 aliases M       (dead before layer loop)
    //   w2f  : 8 KB          aliases M+100KB (dead before layer loop)
    char* ws = (char*)d_ws;
    __half*         ea   = (__half*)ws;
    __half*         Ah   = (__half*)(ws + 102400000);
    unsigned short* rows = (unsigned short*)(ws + 108800000);
    int*            off  = (int*)(ws + 110400000);
    __half*         M    = (__half*)(ws + 110600016);
    int*            part = (int*)M;
    __half*         w2f  = (__half*)((char*)M + 100000);

    (void)hipMemsetAsync(off, 0, (NN + 1) * sizeof(int), stream);
    k_deg<<<NE / 256, 256, 0, stream>>>(ei, off);
    k_scanA<<<SCAN_BLOCKS, 256, 0, stream>>>(off, part);
    k_scanB<<<1, 256, 0, stream>>>(part);
    k_scanC<<<SCAN_BLOCKS, 256, 0, stream>>>(off, part);
    k_prep<<<1, 256, 0, stream>>>(ew2, w2f);
    k_input<<<NN / 4, 256, 0, stream>>>(x, in_w, in_b, Ah);
    k_edge<<<NE / 256, 256, 0, stream>>>(x, ei, ew1, eb1, eb2, w2f, off, rows, ea);

    const int nodeBlocks = (NN + 63) / 64;     // 782
    for (int l = 0; l < 4; ++l) {
        k_agg<<<NN / 4, 256, 0, stream>>>(Ah, ea, rows, off, M);
        k_node<<<nodeBlocks, 256, 0, stream>>>(Ah, M,
            cw1 + (size_t)l * 4096, cb1 + (size_t)l * 64,
            cw2 + (size_t)l * 4096, cb2 + (size_t)l * 64,
            lnw + (size_t)l * 64,   lnb + (size_t)l * 64);
    }
    k_final<<<(NN + 31) / 32, 256, 0, stream>>>(Ah, fw, fb, rw, rb, ow, ob, out);
}

// Round 12
// 406.441 us; speedup vs baseline: 1.5129x; 1.2526x over previous
//
#include <hip/hip_runtime.h>
#include <hip/hip_fp16.h>
#include <stdint.h>

#define NN 50000
#define NE 800000
#define SCAN_BLOCKS 196   // 196*256 = 50176 >= NN

typedef _Float16 half8v __attribute__((ext_vector_type(8)));
typedef float f32x4 __attribute__((ext_vector_type(4)));

static __device__ __forceinline__ __half2 u2h2(unsigned int u) {
    union { unsigned int u; __half2 h; } c; c.u = u; return c.h;
}
static __device__ __forceinline__ unsigned int h22u(__half2 h) {
    union { __half2 h; unsigned int u; } c; c.h = h; return c.u;
}

static __device__ __forceinline__ float4 fma4(float4 a, float s, float4 w) {
    a.x = fmaf(s, w.x, a.x); a.y = fmaf(s, w.y, a.y);
    a.z = fmaf(s, w.z, a.z); a.w = fmaf(s, w.w, a.w);
    return a;
}
// acc[8] += relu(h + e); h/e = 16B of packed fp16, math in fp32
static __device__ __forceinline__ void acc8(float* acc, float4 hv, float4 ev) {
    const unsigned int* hu = (const unsigned int*)&hv;
    const unsigned int* eu = (const unsigned int*)&ev;
    #pragma unroll
    for (int q = 0; q < 4; ++q) {
        float2 hf = __half22float2(u2h2(hu[q]));
        float2 ef = __half22float2(u2h2(eu[q]));
        acc[q * 2]     += fmaxf(hf.x + ef.x, 0.f);
        acc[q * 2 + 1] += fmaxf(hf.y + ef.y, 0.f);
    }
}

// ---------- CSR build ----------
__global__ __launch_bounds__(256) void k_deg(const int* __restrict__ ei, int* __restrict__ offcur) {
    int e = blockIdx.x * 256 + threadIdx.x;
    atomicAdd(&offcur[ei[NE + e]], 1);
}

__global__ __launch_bounds__(256) void k_scanA(const int* __restrict__ off, int* __restrict__ part) {
    __shared__ int s[256];
    int t = threadIdx.x;
    int idx = blockIdx.x * 256 + t;
    int d = (idx < NN) ? off[idx] : 0;
    s[t] = d; __syncthreads();
    for (int o = 128; o > 0; o >>= 1) {
        if (t < o) s[t] += s[t + o];
        __syncthreads();
    }
    if (t == 0) part[blockIdx.x] = s[0];
}

__global__ __launch_bounds__(256) void k_scanB(int* __restrict__ part) {
    __shared__ int s[256];
    int t = threadIdx.x;
    int d = (t < SCAN_BLOCKS) ? part[t] : 0;
    s[t] = d; __syncthreads();
    #pragma unroll
    for (int o = 1; o < 256; o <<= 1) {
        int v = (t >= o) ? s[t - o] : 0;
        __syncthreads();
        s[t] += v;
        __syncthreads();
    }
    if (t < SCAN_BLOCKS) part[t] = s[t] - d;   // exclusive
}

__global__ __launch_bounds__(256) void k_scanC(int* __restrict__ off, const int* __restrict__ part) {
    __shared__ int s[256];
    int t = threadIdx.x;
    int idx = blockIdx.x * 256 + t;
    int d = (idx < NN) ? off[idx] : 0;
    s[t] = d; __syncthreads();
    #pragma unroll
    for (int o = 1; o < 256; o <<= 1) {
        int v = (t >= o) ? s[t - o] : 0;
        __syncthreads();
        s[t] += v;
        __syncthreads();
    }
    if (idx < NN) off[idx] = s[t] - d + part[blockIdx.x];
}

// ---------- weight prep: 9 f32 64x64 matrices -> fp16 MFMA B-fragments ----------
// blockIdx 0: ew2 ; blockIdx 1+2l: cw1[l] ; blockIdx 2+2l: cw2[l]
__global__ __launch_bounds__(256) void k_prep(const float* __restrict__ ew2,
        const float* __restrict__ cw1, const float* __restrict__ cw2,
        __half* __restrict__ wf) {
    int b = blockIdx.x;
    const float* src;
    if (b == 0) src = ew2;
    else {
        int l = (b - 1) >> 1;
        src = ((b - 1) & 1) ? (cw2 + (size_t)l * 4096) : (cw1 + (size_t)l * 4096);
    }
    __half* dst = wf + (size_t)b * 4096;
    int tid = threadIdx.x;
    for (int i = tid; i < 4096; i += 256) {
        int k = i >> 6, n = i & 63;
        int kt = k >> 5, kin = k & 31;
        int quad = kin >> 3, j = kin & 7;
        int nt = n >> 4, nin = n & 15;
        dst[(size_t)((kt * 4 + nt) * 64 + quad * 16 + nin) * 8 + j] = __float2half(src[i]);
    }
}

// ---------- h init (fp16 shadow store) ----------
__global__ __launch_bounds__(256) void k_input(const float* __restrict__ x,
        const float* __restrict__ in_w, const float* __restrict__ in_b,
        __half* __restrict__ Ah) {
    int n = blockIdx.x * 4 + (threadIdx.x >> 6);
    int k = threadIdx.x & 63;
    const float* xr = x + (size_t)n * 3;
    float v = in_b[k] + xr[0] * in_w[k] + xr[1] * in_w[64 + k] + xr[2] * in_w[128 + k];
    Ah[(size_t)n * 64 + k] = __float2half(v);
}

// ---------- edge MLP -> ea (fp16) via f16 MFMA, fused CSR scatter ----------
__global__ __launch_bounds__(256) void k_edge(const float* __restrict__ x,
        const int* __restrict__ ei,
        const float* __restrict__ ew1, const float* __restrict__ eb1,
        const float* __restrict__ eb2, const __half* __restrict__ w2f,
        int* __restrict__ offcur, unsigned short* __restrict__ rows,
        __half* __restrict__ ea) {
    __shared__ float s_w1[128], s_b1[64], s_b2[64];
    __shared__ float s_rx[256], s_ry[256];
    __shared__ int s_pos[256];
    __shared__ __half s_d[4][16][80];   // per-wave staging
    int tid = threadIdx.x, lane = tid & 63, w = tid >> 6;

    half8v bf[8];
    {
        const half8v* W2F = (const half8v*)w2f;
        #pragma unroll
        for (int f = 0; f < 8; ++f) bf[f] = W2F[f * 64 + lane];
    }
    if (tid < 128) s_w1[tid] = ew1[tid];
    if (tid < 64) s_b1[tid] = eb1[tid];
    else if (tid < 128) s_b2[tid - 64] = eb2[tid - 64];
    int eb = blockIdx.x * 256;
    int my_r, my_pos;
    {
        int e = eb + tid;
        int r = ei[e], c = ei[NE + e];
        s_rx[tid] = x[(size_t)c * 3]     - x[(size_t)r * 3];
        s_ry[tid] = x[(size_t)c * 3 + 1] - x[(size_t)r * 3 + 1];
        int pos = atomicAdd(&offcur[c], 1);
        my_r = r; my_pos = pos;        // rows[] store deferred to kernel end
        s_pos[tid] = pos;
    }
    __syncthreads();

    int lm = lane & 15, lq = lane >> 4;
    #pragma unroll
    for (int t = 0; t < 4; ++t) {
        int ebase = w * 64 + t * 16;
        float rx = s_rx[ebase + lm], ry = s_ry[ebase + lm];
        half8v a0, a1;
        #pragma unroll
        for (int j = 0; j < 8; ++j) {
            int k0 = lq * 8 + j;
            a0[j] = (_Float16)fmaxf(fmaf(rx, s_w1[k0], fmaf(ry, s_w1[64 + k0], s_b1[k0])), 0.f);
            int k1 = k0 + 32;
            a1[j] = (_Float16)fmaxf(fmaf(rx, s_w1[k1], fmaf(ry, s_w1[64 + k1], s_b1[k1])), 0.f);
        }
        f32x4 acc[4];
        #pragma unroll
        for (int nt = 0; nt < 4; ++nt) {
            float b = s_b2[nt * 16 + lm];
            acc[nt][0] = b; acc[nt][1] = b; acc[nt][2] = b; acc[nt][3] = b;
            acc[nt] = __builtin_amdgcn_mfma_f32_16x16x32_f16(a0, bf[nt],     acc[nt], 0, 0, 0);
            acc[nt] = __builtin_amdgcn_mfma_f32_16x16x32_f16(a1, bf[4 + nt], acc[nt], 0, 0, 0);
        }
        // epilogue: C/D layout col=lane&15, row=(lane>>4)*4+reg -> wave-private LDS
        __builtin_amdgcn_wave_barrier();
        #pragma unroll
        for (int nt = 0; nt < 4; ++nt)
            #pragma unroll
            for (int r = 0; r < 4; ++r)
                s_d[w][lq * 4 + r][nt * 16 + lm] = __float2half(acc[nt][r]);
        __builtin_amdgcn_wave_barrier();
        int row = lane >> 2, seg = lane & 3;
        int pos = s_pos[w * 64 + t * 16 + row];
        uint4 v0 = *(const uint4*)&s_d[w][row][seg * 16];
        uint4 v1 = *(const uint4*)&s_d[w][row][seg * 16 + 8];
        uint4* dst = (uint4*)&ea[(size_t)pos * 64 + seg * 16];
        dst[0] = v0;
        dst[1] = v1;
        __builtin_amdgcn_wave_barrier();
    }
    rows[my_pos] = (unsigned short)my_r;   // deferred scatter, off critical path
}

// ---------- per-layer: gather aggregate ----------
// wave per node; lane = es (8 edge sublanes) x oc (8 channel octets of 16B).
__global__ __launch_bounds__(256) void k_agg(const __half* __restrict__ Ah,
        const __half* __restrict__ ea, const unsigned short* __restrict__ rows,
        const int* __restrict__ offcur, __half* __restrict__ M) {
    const float4* A4 = (const float4*)Ah;   // 8 fp16 per float4
    const float4* E4 = (const float4*)ea;
    int w = threadIdx.x >> 6, lane = threadIdx.x & 63;
    int es = lane >> 3, oc = lane & 7;
    int n = blockIdx.x * 4 + w;
    int p0 = (n == 0) ? 0 : offcur[n - 1];
    int p1 = offcur[n];
    float acc[8] = {0,0,0,0,0,0,0,0};
    float accB[8] = {0,0,0,0,0,0,0,0};
    for (int base = p0; base < p1; base += 64) {
        int cnt = min(64, p1 - base);
        int rl = (int)rows[base + min(lane, cnt - 1)];
        int j = 0;
        for (; j + 16 <= cnt; j += 16) {
            int i0 = j + es, i1 = j + 8 + es;
            int r0 = __shfl(rl, i0, 64);
            int r1 = __shfl(rl, i1, 64);
            float4 h0 = A4[(size_t)r0 * 8 + oc];
            float4 h1 = A4[(size_t)r1 * 8 + oc];
            float4 e0 = E4[(size_t)(base + i0) * 8 + oc];
            float4 e1 = E4[(size_t)(base + i1) * 8 + oc];
            acc8(acc, h0, e0);
            acc8(accB, h1, e1);
        }
        for (; j < cnt; j += 8) {
            int i0 = j + es;
            bool valid = i0 < cnt;
            int ic = valid ? i0 : (cnt - 1);
            int r0 = __shfl(rl, ic, 64);
            float4 h0 = A4[(size_t)r0 * 8 + oc];
            float4 e0 = E4[(size_t)(base + ic) * 8 + oc];
            if (valid) acc8(acc, h0, e0);
        }
    }
    #pragma unroll
    for (int q = 0; q < 8; ++q) acc[q] += accB[q];
    #pragma unroll
    for (int m = 8; m < 64; m <<= 1) {
        #pragma unroll
        for (int q = 0; q < 8; ++q) acc[q] += __shfl_xor(acc[q], m, 64);
    }
    if (es == 0) {
        float4 sv = A4[(size_t)n * 8 + oc];
        const unsigned int* su = (const unsigned int*)&sv;
        unsigned int o[4];
        #pragma unroll
        for (int q = 0; q < 4; ++q) {
            float2 sf = __half22float2(u2h2(su[q]));
            o[q] = h22u(__floats2half2_rn(sf.x + acc[q * 2], sf.y + acc[q * 2 + 1]));
        }
        *(uint4*)&M[(size_t)n * 64 + oc * 8] = *(uint4*)&o[0];
    }
}

// ---------- per-layer: node MLP via f16 MFMA + LN + gelu + residual ----------
// block = 64 nodes (4 waves x 16). A-frags straight from fp16 M; u-transpose via
// wave-private LDS; LN over lm-lanes with shfl_xor; verified layouts from k_edge.
__global__ __launch_bounds__(256) void k_node(__half* __restrict__ Ah, const __half* __restrict__ M,
        const __half* __restrict__ w1f, const __half* __restrict__ w2f,
        const float* __restrict__ cb1, const float* __restrict__ cb2,
        const float* __restrict__ lnw, const float* __restrict__ lnb) {
    __shared__ __half s_u[4][16][72];   // per-wave 16 nodes x 64 ch (pad 72)
    __shared__ float s_b1[64], s_b2[64], s_g[64], s_bt[64];
    int tid = threadIdx.x, lane = tid & 63, w = tid >> 6;
    int lm = lane & 15, lq = lane >> 4;

    half8v bw1[8], bw2[8];
    {
        const half8v* W1F = (const half8v*)w1f;
        const half8v* W2F = (const half8v*)w2f;
        #pragma unroll
        for (int f = 0; f < 8; ++f) { bw1[f] = W1F[f * 64 + lane]; bw2[f] = W2F[f * 64 + lane]; }
    }
    if (tid < 64) { s_b1[tid] = cb1[tid]; s_g[tid] = lnw[tid]; }
    else if (tid < 128) { s_b2[tid - 64] = cb2[tid - 64]; s_bt[tid - 64] = lnb[tid - 64]; }
    __syncthreads();

    int nb = blockIdx.x * 64;
    int na = nb + w * 16 + lm;
    int nac = min(na, NN - 1);          // clamp for tail block (output guarded)

    // ---- matmul1: u = relu(M @ W1 + b1), A-frags direct from M ----
    const uint4* M4 = (const uint4*)M;
    uint4 a0u = M4[(size_t)nac * 8 + lq];        // k = lq*8..+7
    uint4 a1u = M4[(size_t)nac * 8 + 4 + lq];    // k = 32+lq*8..+7
    half8v a0 = *(const half8v*)&a0u;
    half8v a1 = *(const half8v*)&a1u;

    f32x4 acc[4];
    #pragma unroll
    for (int nt = 0; nt < 4; ++nt) {
        float b = s_b1[nt * 16 + lm];
        acc[nt][0] = b; acc[nt][1] = b; acc[nt][2] = b; acc[nt][3] = b;
        acc[nt] = __builtin_amdgcn_mfma_f32_16x16x32_f16(a0, bw1[nt],     acc[nt], 0, 0, 0);
        acc[nt] = __builtin_amdgcn_mfma_f32_16x16x32_f16(a1, bw1[4 + nt], acc[nt], 0, 0, 0);
    }
    // stage relu(u) in A-layout source: C layout row=lq*4+r (node), col=nt*16+lm (ch)
    __builtin_amdgcn_wave_barrier();
    #pragma unroll
    for (int nt = 0; nt < 4; ++nt)
        #pragma unroll
        for (int r = 0; r < 4; ++r)
            s_u[w][lq * 4 + r][nt * 16 + lm] = __float2half(fmaxf(acc[nt][r], 0.f));
    __builtin_amdgcn_wave_barrier();

    // ---- matmul2: v = u @ W2 + b2 ----
    half8v u0 = *(const half8v*)&s_u[w][lm][lq * 8];
    half8v u1 = *(const half8v*)&s_u[w][lm][32 + lq * 8];
    #pragma unroll
    for (int nt = 0; nt < 4; ++nt) {
        float b = s_b2[nt * 16 + lm];
        acc[nt][0] = b; acc[nt][1] = b; acc[nt][2] = b; acc[nt][3] = b;
        acc[nt] = __builtin_amdgcn_mfma_f32_16x16x32_f16(u0, bw2[nt],     acc[nt], 0, 0, 0);
        acc[nt] = __builtin_amdgcn_mfma_f32_16x16x32_f16(u1, bw2[4 + nt], acc[nt], 0, 0, 0);
    }

    // ---- LN per node (rows lq*4+r live across lm-lanes of this lq group) ----
    float S[4], SQ[4];
    #pragma unroll
    for (int r = 0; r < 4; ++r) {
        S[r]  = acc[0][r] + acc[1][r] + acc[2][r] + acc[3][r];
        SQ[r] = acc[0][r] * acc[0][r] + acc[1][r] * acc[1][r]
              + acc[2][r] * acc[2][r] + acc[3][r] * acc[3][r];
    }
    #pragma unroll
    for (int m = 1; m < 16; m <<= 1) {
        #pragma unroll
        for (int r = 0; r < 4; ++r) {
            S[r]  += __shfl_xor(S[r], m, 64);
            SQ[r] += __shfl_xor(SQ[r], m, 64);
        }
    }
    // ---- gelu(LN(v)) staged to s_u (pre-residual) ----
    __builtin_amdgcn_wave_barrier();
    #pragma unroll
    for (int r = 0; r < 4; ++r) {
        float mu  = S[r] * (1.f / 64.f);
        float var = SQ[r] * (1.f / 64.f) - mu * mu;
        float rs  = rsqrtf(var + 1e-5f);
        #pragma unroll
        for (int nt = 0; nt < 4; ++nt) {
            int c = nt * 16 + lm;
            float y = (acc[nt][r] - mu) * rs * s_g[c] + s_bt[c];
            float ge = 0.5f * y * (1.f + erff(y * 0.70710678118654752f));
            s_u[w][lq * 4 + r][c] = __float2half(ge);
        }
    }
    __builtin_amdgcn_wave_barrier();

    // ---- epilogue: Ah[n] += staged gelu (residual), 16B chunks ----
    #pragma unroll
    for (int it = 0; it < 2; ++it) {
        int ck = lq + 4 * it;              // uint4 chunk 0..7
        int n = nb + w * 16 + lm;
        if (n < NN) {
            uint4 ge8 = *(const uint4*)&s_u[w][lm][ck * 8];
            uint4 id8 = *(const uint4*)&Ah[(size_t)n * 64 + ck * 8];
            const unsigned int* gu = (const unsigned int*)&ge8;
            const unsigned int* iu = (const unsigned int*)&id8;
            unsigned int o[4];
            #pragma unroll
            for (int p = 0; p < 4; ++p) {
                float2 gf = __half22float2(u2h2(gu[p]));
                float2 iff = __half22float2(u2h2(iu[p]));
                o[p] = h22u(__floats2half2_rn(gf.x + iff.x, gf.y + iff.y));
            }
            *(uint4*)&Ah[(size_t)n * 64 + ck * 8] = *(uint4*)&o[0];
        }
    }
}

// ---------- final: out = LN(h@(fw+rw) + (fb+rb); ow, ob) ----------
__global__ __launch_bounds__(256) void k_final(const __half* __restrict__ Ah,
        const float* __restrict__ fw, const float* __restrict__ fb,
        const float* __restrict__ rw, const float* __restrict__ rb,
        const float* __restrict__ ow, const float* __restrict__ ob,
        float* __restrict__ out) {
    __shared__ float s_W[64 * 128];     // [k][c] row-major, combined fw+rw
    __shared__ float s_h[32 * 68];
    __shared__ float s_b[128];
    __shared__ float s_red[32][4];
    int tid = threadIdx.x;
    for (int i = tid; i < 8192; i += 256) s_W[i] = fw[i] + rw[i];
    if (tid < 128) s_b[tid] = fb[tid] + rb[tid];
    int nb = blockIdx.x * 32;
    for (int i = tid; i < 2048; i += 256) {
        int nl = i >> 6, k = i & 63;
        int n = nb + nl;
        s_h[nl * 68 + k] = (n < NN) ? __half2float(Ah[(size_t)n * 64 + k]) : 0.f;
    }
    __syncthreads();

    int lane = tid & 63, w = tid >> 6;
    int chh = w & 1, nh = w >> 1;
    int cq = lane & 15, ng = lane >> 4;
    int c0 = chh * 64 + cq * 4;
    int rbase = nh * 16 + ng * 4;

    float4 acc[4];
    {
        float4 bq = *(const float4*)&s_b[c0];
        acc[0] = bq; acc[1] = bq; acc[2] = bq; acc[3] = bq;
    }
    #pragma unroll 4
    for (int k4 = 0; k4 < 16; ++k4) {
        float4 m0 = *(const float4*)&s_h[(rbase + 0) * 68 + k4 * 4];
        float4 m1 = *(const float4*)&s_h[(rbase + 1) * 68 + k4 * 4];
        float4 m2 = *(const float4*)&s_h[(rbase + 2) * 68 + k4 * 4];
        float4 m3 = *(const float4*)&s_h[(rbase + 3) * 68 + k4 * 4];
        #pragma unroll
        for (int kk = 0; kk < 4; ++kk) {
            float4 w4 = *(const float4*)&s_W[(k4 * 4 + kk) * 128 + c0];
            acc[0] = fma4(acc[0], ((const float*)&m0)[kk], w4);
            acc[1] = fma4(acc[1], ((const float*)&m1)[kk], w4);
            acc[2] = fma4(acc[2], ((const float*)&m2)[kk], w4);
            acc[3] = fma4(acc[3], ((const float*)&m3)[kk], w4);
        }
    }
    #pragma unroll
    for (int j = 0; j < 4; ++j) {
        float4 v = acc[j];
        float sum = v.x + v.y + v.z + v.w;
        float sq  = v.x * v.x + v.y * v.y + v.z * v.z + v.w * v.w;
        #pragma unroll
        for (int m = 1; m < 16; m <<= 1) {
            sum += __shfl_xor(sum, m, 64);
            sq  += __shfl_xor(sq, m, 64);
        }
        if (cq == 0) {
            s_red[rbase + j][chh * 2]     = sum;
            s_red[rbase + j][chh * 2 + 1] = sq;
        }
    }
    __syncthreads();
    float4 gq = *(const float4*)&ow[c0];
    float4 bq = *(const float4*)&ob[c0];
    #pragma unroll
    for (int j = 0; j < 4; ++j) {
        int nl = rbase + j;
        int n = nb + nl;
        float tsum = s_red[nl][0] + s_red[nl][2];
        float tsq  = s_red[nl][1] + s_red[nl][3];
        float mu  = tsum * (1.f / 128.f);
        float var = tsq * (1.f / 128.f) - mu * mu;
        float rs  = rsqrtf(var + 1e-5f);
        if (n < NN) {
            float4 v = acc[j];
            float4 o;
            o.x = (v.x - mu) * rs * gq.x + bq.x;
            o.y = (v.y - mu) * rs * gq.y + bq.y;
            o.z = (v.z - mu) * rs * gq.z + bq.z;
            o.w = (v.w - mu) * rs * gq.w + bq.w;
            *(float4*)&out[(size_t)n * 128 + c0] = o;
        }
    }
}

extern "C" void kernel_launch(void* const* d_in, const int* in_sizes, int n_in,
                              void* d_out, int out_size, void* d_ws, size_t ws_size,
                              hipStream_t stream) {
    const float* x    = (const float*)d_in[0];
    const int*   ei   = (const int*)d_in[1];
    const float* in_w = (const float*)d_in[2];
    const float* in_b = (const float*)d_in[3];
    const float* ew1  = (const float*)d_in[4];
    const float* eb1  = (const float*)d_in[5];
    const float* ew2  = (const float*)d_in[6];
    const float* eb2  = (const float*)d_in[7];
    const float* cw1  = (const float*)d_in[8];
    const float* cb1  = (const float*)d_in[9];
    const float* cw2  = (const float*)d_in[10];
    const float* cb2  = (const float*)d_in[11];
    const float* lnw  = (const float*)d_in[12];
    const float* lnb  = (const float*)d_in[13];
    const float* fw   = (const float*)d_in[14];
    const float* fb   = (const float*)d_in[15];
    const float* rw   = (const float*)d_in[16];
    const float* rb   = (const float*)d_in[17];
    const float* ow   = (const float*)d_in[18];
    const float* ob   = (const float*)d_in[19];
    float* out = (float*)d_out;

    // workspace layout (bytes), proven budget >= 123.4 MB:
    //   ea   (fp16): NE*64*2  = 102,400,000  @ 0
    //   Ah   (fp16): NN*64*2  =   6,400,000  @ 102,400,000
    //   rows (u16) : NE*2     =   1,600,000  @ 108,800,000
    //   off        : (NN+1)*4 =     200,016  @ 110,400,000
    //   M    (fp16): NN*64*2  =   6,400,000  @ 110,600,016
    //   wf   (fp16): 9*4096*2 =      73,728  @ 117,000,016  (ends 117,073,744)
    //   part : SCAN_BLOCKS*4 aliases M       (dead before layer loop)
    char* ws = (char*)d_ws;
    __half*         ea   = (__half*)ws;
    __half*         Ah   = (__half*)(ws + 102400000);
    unsigned short* rows = (unsigned short*)(ws + 108800000);
    int*            off  = (int*)(ws + 110400000);
    __half*         M    = (__half*)(ws + 110600016);
    __half*         wf   = (__half*)(ws + 117000016);
    int*            part = (int*)M;

    (void)hipMemsetAsync(off, 0, (NN + 1) * sizeof(int), stream);
    k_deg<<<NE / 256, 256, 0, stream>>>(ei, off);
    k_scanA<<<SCAN_BLOCKS, 256, 0, stream>>>(off, part);
    k_scanB<<<1, 256, 0, stream>>>(part);
    k_scanC<<<SCAN_BLOCKS, 256, 0, stream>>>(off, part);
    k_prep<<<9, 256, 0, stream>>>(ew2, cw1, cw2, wf);
    k_input<<<NN / 4, 256, 0, stream>>>(x, in_w, in_b, Ah);
    k_edge<<<NE / 256, 256, 0, stream>>>(x, ei, ew1, eb1, eb2, wf, off, rows, ea);

    const int nodeBlocks = (NN + 63) / 64;     // 782
    for (int l = 0; l < 4; ++l) {
        k_agg<<<NN / 4, 256, 0, stream>>>(Ah, ea, rows, off, M);
        k_node<<<nodeBlocks, 256, 0, stream>>>(Ah, M,
            wf + (size_t)(1 + 2 * l) * 4096, wf + (size_t)(2 + 2 * l) * 4096,
            cb1 + (size_t)l * 64, cb2 + (size_t)l * 64,
            lnw + (size_t)l * 64, lnb + (size_t)l * 64);
    }
    k_final<<<(NN + 31) / 32, 256, 0, stream>>>(Ah, fw, fb, rw, rb, ow, ob, out);
}